// Round 1
// baseline (953.916 us; speedup 1.0000x reference)
//
#include <hip/hip_runtime.h>
#include <hip/hip_bf16.h>

#define N_NODES 100000
#define N_EDGES 1600000
#define D 128

// ---------------- CSR build ----------------

__global__ void count_deg_kernel(const int* __restrict__ dst, int* __restrict__ deg) {
    int i = blockIdx.x * blockDim.x + threadIdx.x;
    if (i < N_EDGES) atomicAdd(&deg[dst[i]], 1);
}

// single-block scan: row_ptr[0]=0, row_ptr[i+1]=inclusive_sum(deg[0..i])
__global__ void scan_kernel(const int* __restrict__ deg, int* __restrict__ row_ptr, int n) {
    __shared__ int wsum[16];
    __shared__ int carry_s;
    int t = threadIdx.x;
    int lane = t & 63, wv = t >> 6;
    if (t == 0) { carry_s = 0; row_ptr[0] = 0; }
    __syncthreads();
    for (int base = 0; base < n; base += 4096) {
        int idx4 = base + t * 4;
        int v0 = 0, v1 = 0, v2 = 0, v3 = 0;
        if (idx4 + 3 < n) {
            int4 d4 = *(const int4*)&deg[idx4];
            v0 = d4.x; v1 = d4.y; v2 = d4.z; v3 = d4.w;
        } else {
            if (idx4 + 0 < n) v0 = deg[idx4 + 0];
            if (idx4 + 1 < n) v1 = deg[idx4 + 1];
            if (idx4 + 2 < n) v2 = deg[idx4 + 2];
            if (idx4 + 3 < n) v3 = deg[idx4 + 3];
        }
        int s1 = v0 + v1, s2 = s1 + v2, s3 = s2 + v3;
        int tot = s3;
        int scan = tot;
        #pragma unroll
        for (int off = 1; off < 64; off <<= 1) {
            int y = __shfl_up(scan, off);
            if (lane >= off) scan += y;
        }
        if (lane == 63) wsum[wv] = scan;
        __syncthreads();
        if (wv == 0 && lane < 16) {
            int v = wsum[lane];
            int sc = v;
            #pragma unroll
            for (int off = 1; off < 16; off <<= 1) {
                int y = __shfl_up(sc, off);
                if (lane >= off) sc += y;
            }
            wsum[lane] = sc - v;  // exclusive
        }
        __syncthreads();
        int texcl = scan - tot + wsum[wv] + carry_s;
        if (idx4 + 0 < n) row_ptr[idx4 + 1] = texcl + v0;
        if (idx4 + 1 < n) row_ptr[idx4 + 2] = texcl + s1;
        if (idx4 + 2 < n) row_ptr[idx4 + 3] = texcl + s2;
        if (idx4 + 3 < n) row_ptr[idx4 + 4] = texcl + s3;
        __syncthreads();
        if (t == 1023) carry_s = texcl + s3;
        __syncthreads();
    }
}

__global__ void copy_cursor_kernel(const int* __restrict__ row_ptr, int* __restrict__ cursor) {
    int i = blockIdx.x * blockDim.x + threadIdx.x;
    if (i < N_NODES) cursor[i] = row_ptr[i];
}

__global__ void fill_csr_kernel(const int* __restrict__ src, const int* __restrict__ dst,
                                int* __restrict__ cursor, int* __restrict__ col) {
    int i = blockIdx.x * blockDim.x + threadIdx.x;
    if (i < N_EDGES) {
        int p = atomicAdd(&cursor[dst[i]], 1);
        col[p] = src[i];
    }
}

// ---------------- GIN layer ----------------

// one wave per node: h[i] = (1+eps)*x[i] + sum_{e in CSR row i} x[col[e]]
__global__ void aggregate_kernel(const float* __restrict__ xin, const int* __restrict__ row_ptr,
                                 const int* __restrict__ col, const float* __restrict__ eps_p,
                                 float* __restrict__ h) {
    int w = (blockIdx.x * blockDim.x + threadIdx.x) >> 6;
    if (w >= N_NODES) return;
    int lane = threadIdx.x & 63;
    int beg = row_ptr[w], end = row_ptr[w + 1];
    const float2* x2 = (const float2*)xin;
    float2 acc = make_float2(0.f, 0.f);
    for (int e = beg; e < end; ++e) {
        int s = col[e];
        float2 v = x2[(size_t)s * 64 + lane];
        acc.x += v.x;
        acc.y += v.y;
    }
    float scale = 1.0f + *eps_p;
    float2 xi = x2[(size_t)w * 64 + lane];
    acc.x += scale * xi.x;
    acc.y += scale * xi.y;
    ((float2*)h)[(size_t)w * 64 + lane] = acc;
}

// out[n][:] = relu(h[n][:] @ W + b); W(128x128) + 32-row h tile staged in LDS.
// block=256 (4 waves); wave handles 8 nodes; lane handles cols {2l, 2l+1}.
#define TILE_N 32
__launch_bounds__(256, 2)
__global__ void gemm_relu_kernel(const float* __restrict__ hbuf, const float* __restrict__ W,
                                 const float* __restrict__ bias, float* __restrict__ out) {
    __shared__ float Wl[D * D];        // 64 KB
    __shared__ float hl[TILE_N * D];   // 16 KB
    int t = threadIdx.x;
    {
        const float4* W4 = (const float4*)W;
        float4* Wl4 = (float4*)Wl;
        for (int i = t; i < D * D / 4; i += 256) Wl4[i] = W4[i];
    }
    int lane = t & 63;
    int wv = t >> 6;
    float bias0 = bias[2 * lane], bias1 = bias[2 * lane + 1];
    const int ntiles = (N_NODES + TILE_N - 1) / TILE_N;  // 3125, exact
    for (int tile = blockIdx.x; tile < ntiles; tile += gridDim.x) {
        int nbase = tile * TILE_N;
        __syncthreads();  // protect hl reuse across iterations
        {
            const float4* h4 = (const float4*)(hbuf + (size_t)nbase * D);
            float4* hl4 = (float4*)hl;
            for (int i = t; i < TILE_N * D / 4; i += 256) hl4[i] = h4[i];
        }
        __syncthreads();
        float acc[8][2];
        #pragma unroll
        for (int i = 0; i < 8; ++i) { acc[i][0] = 0.f; acc[i][1] = 0.f; }
        const float2* Wl2 = (const float2*)Wl;
        for (int k = 0; k < D; k += 4) {
            float4 hv[8];
            #pragma unroll
            for (int i = 0; i < 8; ++i)
                hv[i] = *(const float4*)&hl[(wv * 8 + i) * D + k];
            #pragma unroll
            for (int kk = 0; kk < 4; ++kk) {
                float2 w2 = Wl2[(k + kk) * 64 + lane];
                #pragma unroll
                for (int i = 0; i < 8; ++i) {
                    float hvk = ((const float*)&hv[i])[kk];
                    acc[i][0] = fmaf(hvk, w2.x, acc[i][0]);
                    acc[i][1] = fmaf(hvk, w2.y, acc[i][1]);
                }
            }
        }
        #pragma unroll
        for (int i = 0; i < 8; ++i) {
            int node = nbase + wv * 8 + i;
            float2 o;
            o.x = fmaxf(acc[i][0] + bias0, 0.f);
            o.y = fmaxf(acc[i][1] + bias1, 0.f);
            ((float2*)out)[(size_t)node * 64 + lane] = o;
        }
    }
}

// in-place row log_softmax, one wave per node
__global__ void log_softmax_kernel(float* __restrict__ y) {
    int w = (blockIdx.x * blockDim.x + threadIdx.x) >> 6;
    if (w >= N_NODES) return;
    int lane = threadIdx.x & 63;
    float2* y2 = (float2*)y;
    float2 v = y2[(size_t)w * 64 + lane];
    float m = fmaxf(v.x, v.y);
    #pragma unroll
    for (int off = 32; off; off >>= 1) m = fmaxf(m, __shfl_xor(m, off));
    float s = expf(v.x - m) + expf(v.y - m);
    #pragma unroll
    for (int off = 32; off; off >>= 1) s += __shfl_xor(s, off);
    float lse = m + logf(s);
    v.x -= lse;
    v.y -= lse;
    y2[(size_t)w * 64 + lane] = v;
}

extern "C" void kernel_launch(void* const* d_in, const int* in_sizes, int n_in,
                              void* d_out, int out_size, void* d_ws, size_t ws_size,
                              hipStream_t stream) {
    (void)in_sizes; (void)n_in; (void)out_size; (void)ws_size;
    const float* x  = (const float*)d_in[0];
    const int*   ei = (const int*)d_in[1];
    const int*   src = ei;
    const int*   dst = ei + N_EDGES;
    const float* W1 = (const float*)d_in[2];
    const float* b1 = (const float*)d_in[3];
    const float* e1 = (const float*)d_in[4];
    const float* W2 = (const float*)d_in[5];
    const float* b2 = (const float*)d_in[6];
    const float* e2 = (const float*)d_in[7];
    const float* W3 = (const float*)d_in[8];
    const float* b3 = (const float*)d_in[9];
    const float* e3 = (const float*)d_in[10];
    float* out = (float*)d_out;

    char* ws = (char*)d_ws;
    int*   row_ptr = (int*)ws;                          // 100001 ints
    int*   cursor  = (int*)(ws + (size_t)(1 << 20));    // 100000 ints
    int*   col     = (int*)(ws + (size_t)(2 << 20));    // 1.6M ints
    float* h       = (float*)(ws + (size_t)(16 << 20)); // 51.2 MB

    hipMemsetAsync(cursor, 0, N_NODES * sizeof(int), stream);
    count_deg_kernel<<<(N_EDGES + 255) / 256, 256, 0, stream>>>(dst, cursor);
    scan_kernel<<<1, 1024, 0, stream>>>(cursor, row_ptr, N_NODES);
    copy_cursor_kernel<<<(N_NODES + 255) / 256, 256, 0, stream>>>(row_ptr, cursor);
    fill_csr_kernel<<<(N_EDGES + 255) / 256, 256, 0, stream>>>(src, dst, cursor, col);

    const int aggGrid = (N_NODES * 64 + 255) / 256;  // one wave per node

    // layer 1
    aggregate_kernel<<<aggGrid, 256, 0, stream>>>(x, row_ptr, col, e1, h);
    gemm_relu_kernel<<<1024, 256, 0, stream>>>(h, W1, b1, out);
    // layer 2
    aggregate_kernel<<<aggGrid, 256, 0, stream>>>(out, row_ptr, col, e2, h);
    gemm_relu_kernel<<<1024, 256, 0, stream>>>(h, W2, b2, out);
    // layer 3
    aggregate_kernel<<<aggGrid, 256, 0, stream>>>(out, row_ptr, col, e3, h);
    gemm_relu_kernel<<<1024, 256, 0, stream>>>(h, W3, b3, out);

    log_softmax_kernel<<<aggGrid, 256, 0, stream>>>(out);
}

// Round 2
// 817.308 us; speedup vs baseline: 1.1671x; 1.1671x over previous
//
#include <hip/hip_runtime.h>
#include <hip/hip_bf16.h>

#define N_NODES 100000
#define N_EDGES 1600000
#define D 128

// ---------------- CSR build ----------------

__global__ void count_deg_kernel(const int* __restrict__ dst, int* __restrict__ deg) {
    int i = blockIdx.x * blockDim.x + threadIdx.x;
    if (i < N_EDGES) atomicAdd(&deg[dst[i]], 1);
}

// single-block scan: row_ptr[0]=0, row_ptr[i+1]=inclusive_sum(deg[0..i])
__global__ void scan_kernel(const int* __restrict__ deg, int* __restrict__ row_ptr, int n) {
    __shared__ int wsum[16];
    __shared__ int carry_s;
    int t = threadIdx.x;
    int lane = t & 63, wv = t >> 6;
    if (t == 0) { carry_s = 0; row_ptr[0] = 0; }
    __syncthreads();
    for (int base = 0; base < n; base += 4096) {
        int idx4 = base + t * 4;
        int v0 = 0, v1 = 0, v2 = 0, v3 = 0;
        if (idx4 + 3 < n) {
            int4 d4 = *(const int4*)&deg[idx4];
            v0 = d4.x; v1 = d4.y; v2 = d4.z; v3 = d4.w;
        } else {
            if (idx4 + 0 < n) v0 = deg[idx4 + 0];
            if (idx4 + 1 < n) v1 = deg[idx4 + 1];
            if (idx4 + 2 < n) v2 = deg[idx4 + 2];
            if (idx4 + 3 < n) v3 = deg[idx4 + 3];
        }
        int s1 = v0 + v1, s2 = s1 + v2, s3 = s2 + v3;
        int tot = s3;
        int scan = tot;
        #pragma unroll
        for (int off = 1; off < 64; off <<= 1) {
            int y = __shfl_up(scan, off);
            if (lane >= off) scan += y;
        }
        if (lane == 63) wsum[wv] = scan;
        __syncthreads();
        if (wv == 0 && lane < 16) {
            int v = wsum[lane];
            int sc = v;
            #pragma unroll
            for (int off = 1; off < 16; off <<= 1) {
                int y = __shfl_up(sc, off);
                if (lane >= off) sc += y;
            }
            wsum[lane] = sc - v;  // exclusive
        }
        __syncthreads();
        int texcl = scan - tot + wsum[wv] + carry_s;
        if (idx4 + 0 < n) row_ptr[idx4 + 1] = texcl + v0;
        if (idx4 + 1 < n) row_ptr[idx4 + 2] = texcl + s1;
        if (idx4 + 2 < n) row_ptr[idx4 + 3] = texcl + s2;
        if (idx4 + 3 < n) row_ptr[idx4 + 4] = texcl + s3;
        __syncthreads();
        if (t == 1023) carry_s = texcl + s3;
        __syncthreads();
    }
}

__global__ void copy_cursor_kernel(const int* __restrict__ row_ptr, int* __restrict__ cursor) {
    int i = blockIdx.x * blockDim.x + threadIdx.x;
    if (i < N_NODES) cursor[i] = row_ptr[i];
}

__global__ void fill_csr_kernel(const int* __restrict__ src, const int* __restrict__ dst,
                                int* __restrict__ cursor, int* __restrict__ col) {
    int i = blockIdx.x * blockDim.x + threadIdx.x;
    if (i < N_EDGES) {
        int p = atomicAdd(&cursor[dst[i]], 1);
        col[p] = src[i];
    }
}

// ---------------- GIN layer ----------------

// half-wave (32 lanes, float4/lane) per node; edge loop unrolled x4 ->
// up to 8 independent 512B row-gathers in flight per wave.
__global__ void aggregate_kernel(const float* __restrict__ xin, const int* __restrict__ row_ptr,
                                 const int* __restrict__ col, const float* __restrict__ eps_p,
                                 float* __restrict__ h) {
    int w = (blockIdx.x * blockDim.x + threadIdx.x) >> 6;
    int lane = threadIdx.x & 63;
    int half = lane >> 5;
    int l32 = lane & 31;
    int node = w * 2 + half;
    if (node >= N_NODES) return;
    int beg = row_ptr[node], end = row_ptr[node + 1];
    const float4* x4 = (const float4*)xin;
    float4 a0 = make_float4(0.f, 0.f, 0.f, 0.f);
    float4 a1 = a0, a2 = a0, a3 = a0;
    int e = beg;
    for (; e + 3 < end; e += 4) {
        int s0 = col[e + 0];
        int s1 = col[e + 1];
        int s2 = col[e + 2];
        int s3 = col[e + 3];
        float4 v0 = x4[(size_t)s0 * 32 + l32];
        float4 v1 = x4[(size_t)s1 * 32 + l32];
        float4 v2 = x4[(size_t)s2 * 32 + l32];
        float4 v3 = x4[(size_t)s3 * 32 + l32];
        a0.x += v0.x; a0.y += v0.y; a0.z += v0.z; a0.w += v0.w;
        a1.x += v1.x; a1.y += v1.y; a1.z += v1.z; a1.w += v1.w;
        a2.x += v2.x; a2.y += v2.y; a2.z += v2.z; a2.w += v2.w;
        a3.x += v3.x; a3.y += v3.y; a3.z += v3.z; a3.w += v3.w;
    }
    for (; e < end; ++e) {
        int s = col[e];
        float4 v = x4[(size_t)s * 32 + l32];
        a0.x += v.x; a0.y += v.y; a0.z += v.z; a0.w += v.w;
    }
    float scale = 1.0f + *eps_p;
    float4 xi = x4[(size_t)node * 32 + l32];
    float4 o;
    o.x = a0.x + a1.x + a2.x + a3.x + scale * xi.x;
    o.y = a0.y + a1.y + a2.y + a3.y + scale * xi.y;
    o.z = a0.z + a1.z + a2.z + a3.z + scale * xi.z;
    o.w = a0.w + a1.w + a2.w + a3.w + scale * xi.w;
    ((float4*)h)[(size_t)node * 32 + l32] = o;
}

// out[n][:] = relu(h[n][:] @ W + b); W(128x128) + 32-row h tile staged in LDS.
// block=256 (4 waves); wave handles 8 nodes; lane handles cols {2l, 2l+1}.
#define TILE_N 32
__launch_bounds__(256, 2)
__global__ void gemm_relu_kernel(const float* __restrict__ hbuf, const float* __restrict__ W,
                                 const float* __restrict__ bias, float* __restrict__ out) {
    __shared__ float Wl[D * D];        // 64 KB
    __shared__ float hl[TILE_N * D];   // 16 KB
    int t = threadIdx.x;
    {
        const float4* W4 = (const float4*)W;
        float4* Wl4 = (float4*)Wl;
        for (int i = t; i < D * D / 4; i += 256) Wl4[i] = W4[i];
    }
    int lane = t & 63;
    int wv = t >> 6;
    float bias0 = bias[2 * lane], bias1 = bias[2 * lane + 1];
    const int ntiles = (N_NODES + TILE_N - 1) / TILE_N;  // 3125, exact
    for (int tile = blockIdx.x; tile < ntiles; tile += gridDim.x) {
        int nbase = tile * TILE_N;
        __syncthreads();  // protect hl reuse across iterations
        {
            const float4* h4 = (const float4*)(hbuf + (size_t)nbase * D);
            float4* hl4 = (float4*)hl;
            for (int i = t; i < TILE_N * D / 4; i += 256) hl4[i] = h4[i];
        }
        __syncthreads();
        float acc[8][2];
        #pragma unroll
        for (int i = 0; i < 8; ++i) { acc[i][0] = 0.f; acc[i][1] = 0.f; }
        const float2* Wl2 = (const float2*)Wl;
        for (int k = 0; k < D; k += 4) {
            float4 hv[8];
            #pragma unroll
            for (int i = 0; i < 8; ++i)
                hv[i] = *(const float4*)&hl[(wv * 8 + i) * D + k];
            #pragma unroll
            for (int kk = 0; kk < 4; ++kk) {
                float2 w2 = Wl2[(k + kk) * 64 + lane];
                #pragma unroll
                for (int i = 0; i < 8; ++i) {
                    float hvk = ((const float*)&hv[i])[kk];
                    acc[i][0] = fmaf(hvk, w2.x, acc[i][0]);
                    acc[i][1] = fmaf(hvk, w2.y, acc[i][1]);
                }
            }
        }
        #pragma unroll
        for (int i = 0; i < 8; ++i) {
            int node = nbase + wv * 8 + i;
            float2 o;
            o.x = fmaxf(acc[i][0] + bias0, 0.f);
            o.y = fmaxf(acc[i][1] + bias1, 0.f);
            ((float2*)out)[(size_t)node * 64 + lane] = o;
        }
    }
}

// in-place row log_softmax, one wave per node
__global__ void log_softmax_kernel(float* __restrict__ y) {
    int w = (blockIdx.x * blockDim.x + threadIdx.x) >> 6;
    if (w >= N_NODES) return;
    int lane = threadIdx.x & 63;
    float2* y2 = (float2*)y;
    float2 v = y2[(size_t)w * 64 + lane];
    float m = fmaxf(v.x, v.y);
    #pragma unroll
    for (int off = 32; off; off >>= 1) m = fmaxf(m, __shfl_xor(m, off));
    float s = expf(v.x - m) + expf(v.y - m);
    #pragma unroll
    for (int off = 32; off; off >>= 1) s += __shfl_xor(s, off);
    float lse = m + logf(s);
    v.x -= lse;
    v.y -= lse;
    y2[(size_t)w * 64 + lane] = v;
}

extern "C" void kernel_launch(void* const* d_in, const int* in_sizes, int n_in,
                              void* d_out, int out_size, void* d_ws, size_t ws_size,
                              hipStream_t stream) {
    (void)in_sizes; (void)n_in; (void)out_size; (void)ws_size;
    const float* x  = (const float*)d_in[0];
    const int*   ei = (const int*)d_in[1];
    const int*   src = ei;
    const int*   dst = ei + N_EDGES;
    const float* W1 = (const float*)d_in[2];
    const float* b1 = (const float*)d_in[3];
    const float* e1 = (const float*)d_in[4];
    const float* W2 = (const float*)d_in[5];
    const float* b2 = (const float*)d_in[6];
    const float* e2 = (const float*)d_in[7];
    const float* W3 = (const float*)d_in[8];
    const float* b3 = (const float*)d_in[9];
    const float* e3 = (const float*)d_in[10];
    float* out = (float*)d_out;

    char* ws = (char*)d_ws;
    int*   row_ptr = (int*)ws;                          // 100001 ints
    int*   cursor  = (int*)(ws + (size_t)(1 << 20));    // 100000 ints
    int*   col     = (int*)(ws + (size_t)(2 << 20));    // 1.6M ints
    float* h       = (float*)(ws + (size_t)(16 << 20)); // 51.2 MB

    hipMemsetAsync(cursor, 0, N_NODES * sizeof(int), stream);
    count_deg_kernel<<<(N_EDGES + 255) / 256, 256, 0, stream>>>(dst, cursor);
    scan_kernel<<<1, 1024, 0, stream>>>(cursor, row_ptr, N_NODES);
    copy_cursor_kernel<<<(N_NODES + 255) / 256, 256, 0, stream>>>(row_ptr, cursor);
    fill_csr_kernel<<<(N_EDGES + 255) / 256, 256, 0, stream>>>(src, dst, cursor, col);

    // one wave per 2 nodes
    const int aggWaves = (N_NODES + 1) / 2;
    const int aggGrid = (aggWaves * 64 + 255) / 256;

    // layer 1
    aggregate_kernel<<<aggGrid, 256, 0, stream>>>(x, row_ptr, col, e1, h);
    gemm_relu_kernel<<<1024, 256, 0, stream>>>(h, W1, b1, out);
    // layer 2
    aggregate_kernel<<<aggGrid, 256, 0, stream>>>(out, row_ptr, col, e2, h);
    gemm_relu_kernel<<<1024, 256, 0, stream>>>(h, W2, b2, out);
    // layer 3
    aggregate_kernel<<<aggGrid, 256, 0, stream>>>(out, row_ptr, col, e3, h);
    gemm_relu_kernel<<<1024, 256, 0, stream>>>(h, W3, b3, out);

    log_softmax_kernel<<<(N_NODES * 64 + 255) / 256, 256, 0, stream>>>(out);
}

// Round 3
// 708.564 us; speedup vs baseline: 1.3463x; 1.1535x over previous
//
#include <hip/hip_runtime.h>
#include <hip/hip_bf16.h>

#define N_NODES 100000
#define N_EDGES 1600000
#define D 128
#define NRANGE 8
#define RANGE_SZ 12500

typedef __attribute__((ext_vector_type(8))) short bf16x8;
typedef __attribute__((ext_vector_type(4))) float f32x4;

__device__ inline ushort f2b(float x) {
    union { float f; unsigned u; } v; v.f = x;
    unsigned r = (v.u + 0x7fff + ((v.u >> 16) & 1)) >> 16;
    return (ushort)r;
}
__device__ inline float b2f(ushort b) {
    union { unsigned u; float f; } v; v.u = ((unsigned)b) << 16;
    return v.f;
}

// ---------------- CSR build (XCD range-split for write locality) ----------------

__global__ void count_deg_kernel(const int* __restrict__ dst, int* __restrict__ deg) {
    int range = blockIdx.x & (NRANGE - 1);   // round-robin XCD heuristic
    int lo = range * RANGE_SZ;
    int hi = lo + RANGE_SZ; if (hi > N_NODES) hi = N_NODES;
    int nb = gridDim.x >> 3;
    int bs = blockIdx.x >> 3;
    int stride = nb * blockDim.x;
    for (int i = bs * blockDim.x + threadIdx.x; i < N_EDGES; i += stride) {
        int d = dst[i];
        if (d >= lo && d < hi) atomicAdd(&deg[d], 1);
    }
}

__global__ void fill_csr_kernel(const int* __restrict__ src, const int* __restrict__ dst,
                                int* __restrict__ cursor, int* __restrict__ col) {
    int range = blockIdx.x & (NRANGE - 1);
    int lo = range * RANGE_SZ;
    int hi = lo + RANGE_SZ; if (hi > N_NODES) hi = N_NODES;
    int nb = gridDim.x >> 3;
    int bs = blockIdx.x >> 3;
    int stride = nb * blockDim.x;
    for (int i = bs * blockDim.x + threadIdx.x; i < N_EDGES; i += stride) {
        int d = dst[i];
        if (d >= lo && d < hi) {
            int p = atomicAdd(&cursor[d], 1);
            col[p] = src[i];
        }
    }
}

// single-block scan: row_ptr[0]=0, row_ptr[i+1]=inclusive_sum(deg[0..i])
__global__ void scan_kernel(const int* __restrict__ deg, int* __restrict__ row_ptr, int n) {
    __shared__ int wsum[16];
    __shared__ int carry_s;
    int t = threadIdx.x;
    int lane = t & 63, wv = t >> 6;
    if (t == 0) { carry_s = 0; row_ptr[0] = 0; }
    __syncthreads();
    for (int base = 0; base < n; base += 4096) {
        int idx4 = base + t * 4;
        int v0 = 0, v1 = 0, v2 = 0, v3 = 0;
        if (idx4 + 3 < n) {
            int4 d4 = *(const int4*)&deg[idx4];
            v0 = d4.x; v1 = d4.y; v2 = d4.z; v3 = d4.w;
        } else {
            if (idx4 + 0 < n) v0 = deg[idx4 + 0];
            if (idx4 + 1 < n) v1 = deg[idx4 + 1];
            if (idx4 + 2 < n) v2 = deg[idx4 + 2];
            if (idx4 + 3 < n) v3 = deg[idx4 + 3];
        }
        int s1 = v0 + v1, s2 = s1 + v2, s3 = s2 + v3;
        int tot = s3;
        int scan = tot;
        #pragma unroll
        for (int off = 1; off < 64; off <<= 1) {
            int y = __shfl_up(scan, off);
            if (lane >= off) scan += y;
        }
        if (lane == 63) wsum[wv] = scan;
        __syncthreads();
        if (wv == 0 && lane < 16) {
            int v = wsum[lane];
            int sc = v;
            #pragma unroll
            for (int off = 1; off < 16; off <<= 1) {
                int y = __shfl_up(sc, off);
                if (lane >= off) sc += y;
            }
            wsum[lane] = sc - v;  // exclusive
        }
        __syncthreads();
        int texcl = scan - tot + wsum[wv] + carry_s;
        if (idx4 + 0 < n) row_ptr[idx4 + 1] = texcl + v0;
        if (idx4 + 1 < n) row_ptr[idx4 + 2] = texcl + s1;
        if (idx4 + 2 < n) row_ptr[idx4 + 3] = texcl + s2;
        if (idx4 + 3 < n) row_ptr[idx4 + 4] = texcl + s3;
        __syncthreads();
        if (t == 1023) carry_s = texcl + s3;
        __syncthreads();
    }
}

__global__ void copy_cursor_kernel(const int* __restrict__ row_ptr, int* __restrict__ cursor) {
    int i = blockIdx.x * blockDim.x + threadIdx.x;
    if (i < N_NODES) cursor[i] = row_ptr[i];
}

// ---------------- GIN layer ----------------

// half-wave (32 lanes, float4/lane) per node; 8 gathers in flight.
// Output: split-precision bf16 pair (h_hi, h_lo) for the MFMA GEMM.
__global__ void aggregate_kernel(const float* __restrict__ xin, const int* __restrict__ row_ptr,
                                 const int* __restrict__ col, const float* __restrict__ eps_p,
                                 ushort* __restrict__ h_hi, ushort* __restrict__ h_lo) {
    int w = (blockIdx.x * blockDim.x + threadIdx.x) >> 6;
    int lane = threadIdx.x & 63;
    int half = lane >> 5;
    int l32 = lane & 31;
    int node = w * 2 + half;
    if (node >= N_NODES) return;
    int beg = row_ptr[node], end = row_ptr[node + 1];
    const float4* x4 = (const float4*)xin;
    float4 a0 = make_float4(0.f, 0.f, 0.f, 0.f);
    float4 a1 = a0, a2 = a0, a3 = a0;
    int e = beg;
    for (; e + 7 < end; e += 8) {
        int s0 = col[e + 0], s1 = col[e + 1], s2 = col[e + 2], s3 = col[e + 3];
        int s4 = col[e + 4], s5 = col[e + 5], s6 = col[e + 6], s7 = col[e + 7];
        float4 v0 = x4[(size_t)s0 * 32 + l32];
        float4 v1 = x4[(size_t)s1 * 32 + l32];
        float4 v2 = x4[(size_t)s2 * 32 + l32];
        float4 v3 = x4[(size_t)s3 * 32 + l32];
        float4 v4 = x4[(size_t)s4 * 32 + l32];
        float4 v5 = x4[(size_t)s5 * 32 + l32];
        float4 v6 = x4[(size_t)s6 * 32 + l32];
        float4 v7 = x4[(size_t)s7 * 32 + l32];
        a0.x += v0.x; a0.y += v0.y; a0.z += v0.z; a0.w += v0.w;
        a1.x += v1.x; a1.y += v1.y; a1.z += v1.z; a1.w += v1.w;
        a2.x += v2.x; a2.y += v2.y; a2.z += v2.z; a2.w += v2.w;
        a3.x += v3.x; a3.y += v3.y; a3.z += v3.z; a3.w += v3.w;
        a0.x += v4.x; a0.y += v4.y; a0.z += v4.z; a0.w += v4.w;
        a1.x += v5.x; a1.y += v5.y; a1.z += v5.z; a1.w += v5.w;
        a2.x += v6.x; a2.y += v6.y; a2.z += v6.z; a2.w += v6.w;
        a3.x += v7.x; a3.y += v7.y; a3.z += v7.z; a3.w += v7.w;
    }
    for (; e + 3 < end; e += 4) {
        int s0 = col[e + 0], s1 = col[e + 1], s2 = col[e + 2], s3 = col[e + 3];
        float4 v0 = x4[(size_t)s0 * 32 + l32];
        float4 v1 = x4[(size_t)s1 * 32 + l32];
        float4 v2 = x4[(size_t)s2 * 32 + l32];
        float4 v3 = x4[(size_t)s3 * 32 + l32];
        a0.x += v0.x; a0.y += v0.y; a0.z += v0.z; a0.w += v0.w;
        a1.x += v1.x; a1.y += v1.y; a1.z += v1.z; a1.w += v1.w;
        a2.x += v2.x; a2.y += v2.y; a2.z += v2.z; a2.w += v2.w;
        a3.x += v3.x; a3.y += v3.y; a3.z += v3.z; a3.w += v3.w;
    }
    for (; e < end; ++e) {
        int s = col[e];
        float4 v = x4[(size_t)s * 32 + l32];
        a0.x += v.x; a0.y += v.y; a0.z += v.z; a0.w += v.w;
    }
    float scale = 1.0f + *eps_p;
    float4 xi = x4[(size_t)node * 32 + l32];
    float4 o;
    o.x = a0.x + a1.x + a2.x + a3.x + scale * xi.x;
    o.y = a0.y + a1.y + a2.y + a3.y + scale * xi.y;
    o.z = a0.z + a1.z + a2.z + a3.z + scale * xi.z;
    o.w = a0.w + a1.w + a2.w + a3.w + scale * xi.w;
    ushort4 hv, lv;
    hv.x = f2b(o.x); lv.x = f2b(o.x - b2f(hv.x));
    hv.y = f2b(o.y); lv.y = f2b(o.y - b2f(hv.y));
    hv.z = f2b(o.z); lv.z = f2b(o.z - b2f(hv.z));
    hv.w = f2b(o.w); lv.w = f2b(o.w - b2f(hv.w));
    *(ushort4*)(h_hi + (size_t)node * D + l32 * 4) = hv;
    *(ushort4*)(h_lo + (size_t)node * D + l32 * 4) = lv;
}

// W[k][n] f32 -> Wt_hi/Wt_lo[n][k] bf16 (transposed, split)
__global__ void wsplit_kernel(const float* __restrict__ W, ushort* __restrict__ wt_hi,
                              ushort* __restrict__ wt_lo) {
    int t = blockIdx.x * blockDim.x + threadIdx.x;
    if (t >= D * D) return;
    int k = t >> 7, n = t & 127;
    float w = W[t];
    ushort hi = f2b(w);
    ushort lo = f2b(w - b2f(hi));
    wt_hi[n * D + k] = hi;
    wt_lo[n * D + k] = lo;
}

// out = relu(h @ W + b) via split-precision bf16 MFMA (hi*hi + hi*lo + lo*hi).
// Block = 4 waves, BM=128 rows; wave handles 32 rows x 128 cols.
// A frag: row = lane&15, k = (lane>>4)*8 + e (8 contiguous bf16).
// B frag: col = lane&15, same k layout -> read from transposed Wt[n][k].
// C/D:    col = lane&15, row = (lane>>4)*4 + reg   [verified layout]
__launch_bounds__(256, 2)
__global__ void gemm_relu_mfma(const ushort* __restrict__ h_hi, const ushort* __restrict__ h_lo,
                               const ushort* __restrict__ wt_hi, const ushort* __restrict__ wt_lo,
                               const float* __restrict__ bias, float* __restrict__ out) {
    int wv = threadIdx.x >> 6, lane = threadIdx.x & 63;
    int r0 = blockIdx.x * 128 + wv * 32;
    int arow = lane & 15, agrp = lane >> 4;
    bf16x8 Ah[2][4], Al[2][4];
    #pragma unroll
    for (int mf = 0; mf < 2; ++mf) {
        size_t rbase = (size_t)(r0 + mf * 16 + arow) * D;
        #pragma unroll
        for (int kf = 0; kf < 4; ++kf) {
            int k0 = kf * 32 + agrp * 8;
            Ah[mf][kf] = *(const bf16x8*)(h_hi + rbase + k0);
            Al[mf][kf] = *(const bf16x8*)(h_lo + rbase + k0);
        }
    }
    f32x4 acc[2][8];
    #pragma unroll
    for (int mf = 0; mf < 2; ++mf)
        #pragma unroll
        for (int nf = 0; nf < 8; ++nf)
            acc[mf][nf] = (f32x4){0.f, 0.f, 0.f, 0.f};
    #pragma unroll
    for (int nf = 0; nf < 8; ++nf) {
        #pragma unroll
        for (int kf = 0; kf < 4; ++kf) {
            size_t wb = (size_t)(nf * 16 + arow) * D + kf * 32 + agrp * 8;
            bf16x8 bh = *(const bf16x8*)(wt_hi + wb);
            bf16x8 bl = *(const bf16x8*)(wt_lo + wb);
            #pragma unroll
            for (int mf = 0; mf < 2; ++mf) {
                acc[mf][nf] = __builtin_amdgcn_mfma_f32_16x16x32_bf16(Ah[mf][kf], bh, acc[mf][nf], 0, 0, 0);
                acc[mf][nf] = __builtin_amdgcn_mfma_f32_16x16x32_bf16(Al[mf][kf], bh, acc[mf][nf], 0, 0, 0);
                acc[mf][nf] = __builtin_amdgcn_mfma_f32_16x16x32_bf16(Ah[mf][kf], bl, acc[mf][nf], 0, 0, 0);
            }
        }
    }
    int crow = agrp * 4;
    #pragma unroll
    for (int mf = 0; mf < 2; ++mf) {
        #pragma unroll
        for (int nf = 0; nf < 8; ++nf) {
            int coln = nf * 16 + arow;
            float b = bias[coln];
            #pragma unroll
            for (int r = 0; r < 4; ++r) {
                int row = r0 + mf * 16 + crow + r;
                if (row < N_NODES)
                    out[(size_t)row * D + coln] = fmaxf(acc[mf][nf][r] + b, 0.f);
            }
        }
    }
}

// in-place row log_softmax, one wave per node
__global__ void log_softmax_kernel(float* __restrict__ y) {
    int w = (blockIdx.x * blockDim.x + threadIdx.x) >> 6;
    if (w >= N_NODES) return;
    int lane = threadIdx.x & 63;
    float2* y2 = (float2*)y;
    float2 v = y2[(size_t)w * 64 + lane];
    float m = fmaxf(v.x, v.y);
    #pragma unroll
    for (int off = 32; off; off >>= 1) m = fmaxf(m, __shfl_xor(m, off));
    float s = expf(v.x - m) + expf(v.y - m);
    #pragma unroll
    for (int off = 32; off; off >>= 1) s += __shfl_xor(s, off);
    float lse = m + logf(s);
    v.x -= lse;
    v.y -= lse;
    y2[(size_t)w * 64 + lane] = v;
}

extern "C" void kernel_launch(void* const* d_in, const int* in_sizes, int n_in,
                              void* d_out, int out_size, void* d_ws, size_t ws_size,
                              hipStream_t stream) {
    (void)in_sizes; (void)n_in; (void)out_size; (void)ws_size;
    const float* x  = (const float*)d_in[0];
    const int*   ei = (const int*)d_in[1];
    const int*   src = ei;
    const int*   dst = ei + N_EDGES;
    const float* W1 = (const float*)d_in[2];
    const float* b1 = (const float*)d_in[3];
    const float* e1 = (const float*)d_in[4];
    const float* W2 = (const float*)d_in[5];
    const float* b2 = (const float*)d_in[6];
    const float* e2 = (const float*)d_in[7];
    const float* W3 = (const float*)d_in[8];
    const float* b3 = (const float*)d_in[9];
    const float* e3 = (const float*)d_in[10];
    float* out = (float*)d_out;

    char* ws = (char*)d_ws;
    int*    row_ptr = (int*)ws;                              // 400 KB
    int*    cursor  = (int*)(ws + (size_t)(1 << 20));        // 400 KB
    int*    col     = (int*)(ws + (size_t)(2 << 20));        // 6.4 MB
    ushort* wt_hi   = (ushort*)(ws + (size_t)(8704 << 10));  // 32 KB @ 8.5MB
    ushort* wt_lo   = (ushort*)(ws + (size_t)(8768 << 10));  // 32 KB
    ushort* h_hi    = (ushort*)(ws + (size_t)(9 << 20));     // 25.6 MB
    ushort* h_lo    = (ushort*)(ws + (size_t)(36 << 20));    // 25.6 MB

    hipMemsetAsync(cursor, 0, N_NODES * sizeof(int), stream);
    count_deg_kernel<<<2048, 256, 0, stream>>>(dst, cursor);
    scan_kernel<<<1, 1024, 0, stream>>>(cursor, row_ptr, N_NODES);
    copy_cursor_kernel<<<(N_NODES + 255) / 256, 256, 0, stream>>>(row_ptr, cursor);
    fill_csr_kernel<<<2048, 256, 0, stream>>>(src, dst, cursor, col);

    const int aggWaves = (N_NODES + 1) / 2;
    const int aggGrid = (aggWaves * 64 + 255) / 256;
    const int gemmGrid = (N_NODES + 127) / 128;  // 782

    // layer 1
    aggregate_kernel<<<aggGrid, 256, 0, stream>>>(x, row_ptr, col, e1, h_hi, h_lo);
    wsplit_kernel<<<64, 256, 0, stream>>>(W1, wt_hi, wt_lo);
    gemm_relu_mfma<<<gemmGrid, 256, 0, stream>>>(h_hi, h_lo, wt_hi, wt_lo, b1, out);
    // layer 2
    aggregate_kernel<<<aggGrid, 256, 0, stream>>>(out, row_ptr, col, e2, h_hi, h_lo);
    wsplit_kernel<<<64, 256, 0, stream>>>(W2, wt_hi, wt_lo);
    gemm_relu_mfma<<<gemmGrid, 256, 0, stream>>>(h_hi, h_lo, wt_hi, wt_lo, b2, out);
    // layer 3
    aggregate_kernel<<<aggGrid, 256, 0, stream>>>(out, row_ptr, col, e3, h_hi, h_lo);
    wsplit_kernel<<<64, 256, 0, stream>>>(W3, wt_hi, wt_lo);
    gemm_relu_mfma<<<gemmGrid, 256, 0, stream>>>(h_hi, h_lo, wt_hi, wt_lo, b3, out);

    log_softmax_kernel<<<(N_NODES * 64 + 255) / 256, 256, 0, stream>>>(out);
}

// Round 4
// 521.863 us; speedup vs baseline: 1.8279x; 1.3578x over previous
//
#include <hip/hip_runtime.h>
#include <hip/hip_bf16.h>

#define N_NODES 100000
#define N_EDGES 1600000
#define D 128
#define NRANGE 8
#define RANGE_SZ 12500
#define G_PART 512
#define CH_PART 3125        // 512*3125 = 1,600,000 exact
#define G_SCAT 2048
#define CH_SCAT ((N_EDGES + G_SCAT - 1) / G_SCAT)
#define SCAN_CH 4096
#define NBS ((N_NODES + SCAN_CH - 1) / SCAN_CH)   // 25

typedef __attribute__((ext_vector_type(8))) short bf16x8;
typedef __attribute__((ext_vector_type(8))) unsigned short u16x8;
typedef __attribute__((ext_vector_type(4))) float f32x4;
typedef unsigned long long u64;

__device__ inline ushort f2b(float x) {
    union { float f; unsigned u; } v; v.f = x;
    unsigned r = (v.u + 0x7fff + ((v.u >> 16) & 1)) >> 16;
    return (ushort)r;
}
__device__ inline float b2f(ushort b) {
    union { unsigned u; float f; } v; v.u = ((unsigned)b) << 16;
    return v.f;
}

// ---------------- x -> bf16 ----------------
__global__ void x2b_kernel(const float* __restrict__ x, ushort* __restrict__ xb) {
    int i = blockIdx.x * blockDim.x + threadIdx.x;
    if (i >= N_NODES * D / 4) return;
    float4 v = ((const float4*)x)[i];
    ushort4 o;
    o.x = f2b(v.x); o.y = f2b(v.y); o.z = f2b(v.z); o.w = f2b(v.w);
    ((ushort4*)xb)[i] = o;
}

// ---------------- CSR build: radix partition by dst range ----------------

__global__ void part_hist_kernel(const int* __restrict__ dst, int* __restrict__ bhist) {
    __shared__ int lh[NRANGE];
    if (threadIdx.x < NRANGE) lh[threadIdx.x] = 0;
    __syncthreads();
    int s0 = blockIdx.x * CH_PART, s1 = s0 + CH_PART;
    if (s1 > N_EDGES) s1 = N_EDGES;
    for (int i = s0 + threadIdx.x; i < s1; i += 256)
        atomicAdd(&lh[dst[i] / RANGE_SZ], 1);
    __syncthreads();
    if (threadIdx.x < NRANGE) bhist[blockIdx.x * NRANGE + threadIdx.x] = lh[threadIdx.x];
}

// 512 threads = 8 waves; wave r scans range r's 512 per-block counts
__global__ void hist_scan_kernel(const int* __restrict__ bhist, int* __restrict__ cursor_base) {
    int r = threadIdx.x >> 6, lane = threadIdx.x & 63;
    __shared__ int rtot[NRANGE], roff[NRANGE];
    int excl[8];
    int run = 0;
    #pragma unroll
    for (int seg = 0; seg < 8; ++seg) {
        int b = seg * 64 + lane;
        int v = bhist[b * NRANGE + r];
        int sc = v;
        #pragma unroll
        for (int off = 1; off < 64; off <<= 1) {
            int y = __shfl_up(sc, off);
            if (lane >= off) sc += y;
        }
        excl[seg] = run + sc - v;
        run += __shfl(sc, 63);
    }
    if (lane == 63) rtot[r] = run;
    __syncthreads();
    if (threadIdx.x == 0) {
        int a = 0;
        for (int i = 0; i < NRANGE; ++i) { roff[i] = a; a += rtot[i]; }
    }
    __syncthreads();
    int base = roff[r];
    #pragma unroll
    for (int seg = 0; seg < 8; ++seg)
        cursor_base[(seg * 64 + lane) * NRANGE + r] = base + excl[seg];
}

__global__ void part_place_kernel(const int* __restrict__ src, const int* __restrict__ dst,
                                  const int* __restrict__ cursor_base, u64* __restrict__ epair) {
    __shared__ int cur[NRANGE];
    if (threadIdx.x < NRANGE) cur[threadIdx.x] = cursor_base[blockIdx.x * NRANGE + threadIdx.x];
    __syncthreads();
    int s0 = blockIdx.x * CH_PART, s1 = s0 + CH_PART;
    if (s1 > N_EDGES) s1 = N_EDGES;
    for (int i = s0 + threadIdx.x; i < s1; i += 256) {
        int d = dst[i], s = src[i];
        int p = atomicAdd(&cur[d / RANGE_SZ], 1);
        epair[p] = ((u64)(unsigned)d << 32) | (unsigned)s;
    }
}

// XCD-swizzled chunking: XCD x gets the contiguous 1/8 of partitioned edges
__device__ inline void scat_range(int* s0, int* s1) {
    int l = (blockIdx.x & 7) * (G_SCAT >> 3) + (blockIdx.x >> 3);
    *s0 = l * CH_SCAT;
    *s1 = *s0 + CH_SCAT;
    if (*s1 > N_EDGES) *s1 = N_EDGES;
}

__global__ void count_deg2_kernel(const u64* __restrict__ epair, int* __restrict__ deg) {
    int s0, s1; scat_range(&s0, &s1);
    for (int i = s0 + threadIdx.x; i < s1; i += 256)
        atomicAdd(&deg[(int)(epair[i] >> 32)], 1);
}

__global__ void fill_csr2_kernel(const u64* __restrict__ epair, int* __restrict__ cursor,
                                 int* __restrict__ col) {
    int s0, s1; scat_range(&s0, &s1);
    for (int i = s0 + threadIdx.x; i < s1; i += 256) {
        u64 e = epair[i];
        int d = (int)(e >> 32), s = (int)(e & 0xffffffffu);
        int p = atomicAdd(&cursor[d], 1);
        col[p] = s;
    }
}

// ---------------- row_ptr scan (25 blocks) ----------------

__global__ void scan_sum_kernel(const int* __restrict__ deg, int* __restrict__ bsum) {
    int s0 = blockIdx.x * SCAN_CH;
    int t = threadIdx.x;
    int sum = 0;
    for (int i = s0 + t; i < s0 + SCAN_CH; i += 256)
        if (i < N_NODES) sum += deg[i];
    #pragma unroll
    for (int off = 32; off; off >>= 1) sum += __shfl_down(sum, off);
    __shared__ int ws[4];
    if ((t & 63) == 0) ws[t >> 6] = sum;
    __syncthreads();
    if (t == 0) bsum[blockIdx.x] = ws[0] + ws[1] + ws[2] + ws[3];
}

__global__ void scan_base_kernel(const int* __restrict__ bsum, int* __restrict__ bbase, int nb) {
    if (threadIdx.x == 0) {
        int run = 0;
        for (int b = 0; b < nb; ++b) { bbase[b] = run; run += bsum[b]; }
    }
}

__global__ void scan_write_kernel(const int* __restrict__ deg, const int* __restrict__ bbase,
                                  int* __restrict__ row_ptr) {
    __shared__ int wsum[16];
    int t = threadIdx.x, lane = t & 63, wv = t >> 6;
    int idx4 = blockIdx.x * SCAN_CH + t * 4;
    int v0 = 0, v1 = 0, v2 = 0, v3 = 0;
    if (idx4 + 3 < N_NODES) {
        int4 d4 = *(const int4*)&deg[idx4];
        v0 = d4.x; v1 = d4.y; v2 = d4.z; v3 = d4.w;
    } else {
        if (idx4 + 0 < N_NODES) v0 = deg[idx4 + 0];
        if (idx4 + 1 < N_NODES) v1 = deg[idx4 + 1];
        if (idx4 + 2 < N_NODES) v2 = deg[idx4 + 2];
        if (idx4 + 3 < N_NODES) v3 = deg[idx4 + 3];
    }
    int s1 = v0 + v1, s2 = s1 + v2, s3 = s2 + v3;
    int scan = s3;
    #pragma unroll
    for (int off = 1; off < 64; off <<= 1) {
        int y = __shfl_up(scan, off);
        if (lane >= off) scan += y;
    }
    if (lane == 63) wsum[wv] = scan;
    __syncthreads();
    if (wv == 0 && lane < 16) {
        int v = wsum[lane];
        int sc = v;
        #pragma unroll
        for (int off = 1; off < 16; off <<= 1) {
            int y = __shfl_up(sc, off);
            if (lane >= off) sc += y;
        }
        wsum[lane] = sc - v;
    }
    __syncthreads();
    int texcl = scan - s3 + wsum[wv] + bbase[blockIdx.x];
    if (idx4 + 0 < N_NODES) row_ptr[idx4 + 1] = texcl + v0;
    if (idx4 + 1 < N_NODES) row_ptr[idx4 + 2] = texcl + s1;
    if (idx4 + 2 < N_NODES) row_ptr[idx4 + 3] = texcl + s2;
    if (idx4 + 3 < N_NODES) row_ptr[idx4 + 4] = texcl + s3;
    if (blockIdx.x == 0 && t == 0) row_ptr[0] = 0;
}

__global__ void copy_cursor_kernel(const int* __restrict__ row_ptr, int* __restrict__ cursor) {
    int i = blockIdx.x * blockDim.x + threadIdx.x;
    if (i < N_NODES) cursor[i] = row_ptr[i];
}

// ---------------- GIN layer ----------------

// quarter-wave (16 lanes x 16B) per node, bf16 gather, 8 edges in flight
__global__ void aggregate_kernel(const ushort* __restrict__ xb, const int* __restrict__ row_ptr,
                                 const int* __restrict__ col, const float* __restrict__ eps_p,
                                 ushort* __restrict__ hb) {
    int gt = blockIdx.x * blockDim.x + threadIdx.x;
    int node = gt >> 4;
    if (node >= N_NODES) return;
    int l16 = threadIdx.x & 15;
    int beg = row_ptr[node], end = row_ptr[node + 1];
    float a0[8] = {0,0,0,0,0,0,0,0};
    float a1[8] = {0,0,0,0,0,0,0,0};
    int e = beg;
    for (; e + 7 < end; e += 8) {
        int s[8];
        #pragma unroll
        for (int j = 0; j < 8; ++j) s[j] = col[e + j];
        u16x8 v[8];
        #pragma unroll
        for (int j = 0; j < 8; ++j)
            v[j] = *(const u16x8*)(xb + ((size_t)s[j] << 7) + l16 * 8);
        #pragma unroll
        for (int j = 0; j < 8; ++j) {
            float* a = (j & 1) ? a1 : a0;
            #pragma unroll
            for (int k = 0; k < 8; ++k) a[k] += b2f(v[j][k]);
        }
    }
    for (; e < end; ++e) {
        int s = col[e];
        u16x8 v = *(const u16x8*)(xb + ((size_t)s << 7) + l16 * 8);
        #pragma unroll
        for (int k = 0; k < 8; ++k) a0[k] += b2f(v[k]);
    }
    float scale = 1.0f + *eps_p;
    u16x8 xi = *(const u16x8*)(xb + ((size_t)node << 7) + l16 * 8);
    u16x8 ho;
    #pragma unroll
    for (int k = 0; k < 8; ++k) {
        float o = a0[k] + a1[k] + scale * b2f(xi[k]);
        ho[k] = f2b(o);
    }
    *(u16x8*)(hb + ((size_t)node << 7) + l16 * 8) = ho;
}

// W[k][n] f32 -> Wt_hi/Wt_lo[n][k] bf16 (transposed, split)
__global__ void wsplit_kernel(const float* __restrict__ W, ushort* __restrict__ wt_hi,
                              ushort* __restrict__ wt_lo) {
    int t = blockIdx.x * blockDim.x + threadIdx.x;
    if (t >= D * D) return;
    int k = t >> 7, n = t & 127;
    float w = W[t];
    ushort hi = f2b(w);
    ushort lo = f2b(w - b2f(hi));
    wt_hi[n * D + k] = hi;
    wt_lo[n * D + k] = lo;
}

// out = relu(h @ W + b); A = bf16 h, W = hi/lo split (2 MFMA per frag pair).
// A frag: row = lane&15, k = (lane>>4)*8 + e. B frag from transposed Wt[n][k].
// C/D: col = lane&15, row = (lane>>4)*4 + reg.
template <bool BF16OUT>
__launch_bounds__(256, 2)
__global__ void gemm_relu_mfma(const ushort* __restrict__ hb,
                               const ushort* __restrict__ wt_hi, const ushort* __restrict__ wt_lo,
                               const float* __restrict__ bias,
                               float* __restrict__ outf, ushort* __restrict__ outb) {
    int wv = threadIdx.x >> 6, lane = threadIdx.x & 63;
    int r0 = blockIdx.x * 128 + wv * 32;
    int arow = lane & 15, agrp = lane >> 4;
    bf16x8 Ah[2][4];
    #pragma unroll
    for (int mf = 0; mf < 2; ++mf) {
        size_t rbase = (size_t)(r0 + mf * 16 + arow) * D;
        #pragma unroll
        for (int kf = 0; kf < 4; ++kf)
            Ah[mf][kf] = *(const bf16x8*)(hb + rbase + kf * 32 + agrp * 8);
    }
    f32x4 acc[2][8];
    #pragma unroll
    for (int mf = 0; mf < 2; ++mf)
        #pragma unroll
        for (int nf = 0; nf < 8; ++nf)
            acc[mf][nf] = (f32x4){0.f, 0.f, 0.f, 0.f};
    #pragma unroll
    for (int nf = 0; nf < 8; ++nf) {
        #pragma unroll
        for (int kf = 0; kf < 4; ++kf) {
            size_t wb = (size_t)(nf * 16 + arow) * D + kf * 32 + agrp * 8;
            bf16x8 bh = *(const bf16x8*)(wt_hi + wb);
            bf16x8 bl = *(const bf16x8*)(wt_lo + wb);
            #pragma unroll
            for (int mf = 0; mf < 2; ++mf) {
                acc[mf][nf] = __builtin_amdgcn_mfma_f32_16x16x32_bf16(Ah[mf][kf], bh, acc[mf][nf], 0, 0, 0);
                acc[mf][nf] = __builtin_amdgcn_mfma_f32_16x16x32_bf16(Ah[mf][kf], bl, acc[mf][nf], 0, 0, 0);
            }
        }
    }
    int crow = agrp * 4;
    #pragma unroll
    for (int mf = 0; mf < 2; ++mf) {
        #pragma unroll
        for (int nf = 0; nf < 8; ++nf) {
            int coln = nf * 16 + arow;
            float b = bias[coln];
            #pragma unroll
            for (int r = 0; r < 4; ++r) {
                int row = r0 + mf * 16 + crow + r;
                if (row < N_NODES) {
                    float val = fmaxf(acc[mf][nf][r] + b, 0.f);
                    if (BF16OUT) outb[(size_t)row * D + coln] = f2b(val);
                    else         outf[(size_t)row * D + coln] = val;
                }
            }
        }
    }
}

// in-place row log_softmax, one wave per node
__global__ void log_softmax_kernel(float* __restrict__ y) {
    int w = (blockIdx.x * blockDim.x + threadIdx.x) >> 6;
    if (w >= N_NODES) return;
    int lane = threadIdx.x & 63;
    float2* y2 = (float2*)y;
    float2 v = y2[(size_t)w * 64 + lane];
    float m = fmaxf(v.x, v.y);
    #pragma unroll
    for (int off = 32; off; off >>= 1) m = fmaxf(m, __shfl_xor(m, off));
    float s = expf(v.x - m) + expf(v.y - m);
    #pragma unroll
    for (int off = 32; off; off >>= 1) s += __shfl_xor(s, off);
    float lse = m + logf(s);
    v.x -= lse;
    v.y -= lse;
    y2[(size_t)w * 64 + lane] = v;
}

extern "C" void kernel_launch(void* const* d_in, const int* in_sizes, int n_in,
                              void* d_out, int out_size, void* d_ws, size_t ws_size,
                              hipStream_t stream) {
    (void)in_sizes; (void)n_in; (void)out_size; (void)ws_size;
    const float* x  = (const float*)d_in[0];
    const int*   ei = (const int*)d_in[1];
    const int*   src = ei;
    const int*   dst = ei + N_EDGES;
    const float* W1 = (const float*)d_in[2];
    const float* b1 = (const float*)d_in[3];
    const float* e1 = (const float*)d_in[4];
    const float* W2 = (const float*)d_in[5];
    const float* b2 = (const float*)d_in[6];
    const float* e2 = (const float*)d_in[7];
    const float* W3 = (const float*)d_in[8];
    const float* b3 = (const float*)d_in[9];
    const float* e3 = (const float*)d_in[10];
    float* out = (float*)d_out;

    char* ws = (char*)d_ws;
    int*    row_ptr     = (int*)ws;                               // 400 KB @ 0
    int*    cursor      = (int*)(ws + (size_t)(512 << 10));       // 400 KB
    int*    bsum        = (int*)(ws + (size_t)(960 << 10));       // 100 B
    int*    bbase       = (int*)(ws + (size_t)(962 << 10));       // 100 B
    int*    bhist       = (int*)(ws + (size_t)(968 << 10));       // 16 KB
    int*    cursor_base = (int*)(ws + (size_t)(984 << 10));       // 16 KB
    int*    col         = (int*)(ws + (size_t)(2 << 20));         // 6.4 MB
    ushort* wt_hi       = (ushort*)(ws + (size_t)(8704 << 10));   // 32 KB
    ushort* wt_lo       = (ushort*)(ws + (size_t)(8768 << 10));   // 32 KB
    ushort* xb          = (ushort*)(ws + (size_t)(9 << 20));      // 25.6 MB -> 34.6
    ushort* hb          = (ushort*)(ws + (size_t)(35 << 20));     // 25.6 MB -> 60.6
    u64*    epair       = (u64*)(ws + (size_t)(35 << 20));        // 12.8 MB (dead before hb's first write)

    x2b_kernel<<<(N_NODES * D / 4 + 255) / 256, 256, 0, stream>>>(x, xb);

    hipMemsetAsync(cursor, 0, N_NODES * sizeof(int), stream);
    part_hist_kernel<<<G_PART, 256, 0, stream>>>(dst, bhist);
    hist_scan_kernel<<<1, 512, 0, stream>>>(bhist, cursor_base);
    part_place_kernel<<<G_PART, 256, 0, stream>>>(src, dst, cursor_base, epair);
    count_deg2_kernel<<<G_SCAT, 256, 0, stream>>>(epair, cursor);
    scan_sum_kernel<<<NBS, 256, 0, stream>>>(cursor, bsum);
    scan_base_kernel<<<1, 64, 0, stream>>>(bsum, bbase, NBS);
    scan_write_kernel<<<NBS, 1024, 0, stream>>>(cursor, bbase, row_ptr);
    copy_cursor_kernel<<<(N_NODES + 255) / 256, 256, 0, stream>>>(row_ptr, cursor);
    fill_csr2_kernel<<<G_SCAT, 256, 0, stream>>>(epair, cursor, col);

    const int aggGrid = (N_NODES * 16 + 255) / 256;   // 6250
    const int gemmGrid = (N_NODES + 127) / 128;       // 782

    // layer 1
    aggregate_kernel<<<aggGrid, 256, 0, stream>>>(xb, row_ptr, col, e1, hb);
    wsplit_kernel<<<64, 256, 0, stream>>>(W1, wt_hi, wt_lo);
    gemm_relu_mfma<true><<<gemmGrid, 256, 0, stream>>>(hb, wt_hi, wt_lo, b1, nullptr, xb);
    // layer 2
    aggregate_kernel<<<aggGrid, 256, 0, stream>>>(xb, row_ptr, col, e2, hb);
    wsplit_kernel<<<64, 256, 0, stream>>>(W2, wt_hi, wt_lo);
    gemm_relu_mfma<true><<<gemmGrid, 256, 0, stream>>>(hb, wt_hi, wt_lo, b2, nullptr, xb);
    // layer 3
    aggregate_kernel<<<aggGrid, 256, 0, stream>>>(xb, row_ptr, col, e3, hb);
    wsplit_kernel<<<64, 256, 0, stream>>>(W3, wt_hi, wt_lo);
    gemm_relu_mfma<false><<<gemmGrid, 256, 0, stream>>>(hb, wt_hi, wt_lo, b3, out, nullptr);

    log_softmax_kernel<<<(N_NODES * 64 + 255) / 256, 256, 0, stream>>>(out);
}

// Round 5
// 409.052 us; speedup vs baseline: 2.3320x; 1.2758x over previous
//
#include <hip/hip_runtime.h>
#include <hip/hip_bf16.h>

#define N_NODES 100000
#define N_EDGES 1600000
#define D 128
#define NRANGE 8
#define RANGE_SZ 12500          // nodes per level-1 range
#define SB_PER_RANGE 196        // 64-node buckets per range (195*64+20 = 12500)
#define NBUCKET (NRANGE * SB_PER_RANGE)  // 1568
#define G_PART 512
#define CH_PART 3125            // 512*3125 = 1,600,000 exact

typedef __attribute__((ext_vector_type(8))) short bf16x8;
typedef __attribute__((ext_vector_type(8))) unsigned short u16x8;
typedef __attribute__((ext_vector_type(4))) float f32x4;
typedef unsigned int u32;

__device__ inline ushort f2b(float x) {
    union { float f; unsigned u; } v; v.f = x;
    unsigned r = (v.u + 0x7fff + ((v.u >> 16) & 1)) >> 16;
    return (ushort)r;
}
__device__ inline float b2f(ushort b) {
    union { unsigned u; float f; } v; v.u = ((unsigned)b) << 16;
    return v.f;
}

// ---------------- x -> bf16 ----------------
__global__ void x2b_kernel(const float* __restrict__ x, ushort* __restrict__ xb) {
    int i = blockIdx.x * blockDim.x + threadIdx.x;
    if (i >= N_NODES * D / 4) return;
    float4 v = ((const float4*)x)[i];
    ushort4 o;
    o.x = f2b(v.x); o.y = f2b(v.y); o.z = f2b(v.z); o.w = f2b(v.w);
    ((ushort4*)xb)[i] = o;
}

// ---------------- CSR build: atomic-free two-level counting sort ----------------

// level-1 histogram: 8 ranges
__global__ void hist1_kernel(const int* __restrict__ dst, int* __restrict__ bhist1) {
    __shared__ int lh[NRANGE];
    if (threadIdx.x < NRANGE) lh[threadIdx.x] = 0;
    __syncthreads();
    int s0 = blockIdx.x * CH_PART, s1 = s0 + CH_PART;
    if (s1 > N_EDGES) s1 = N_EDGES;
    for (int i = s0 + threadIdx.x; i < s1; i += 256)
        atomicAdd(&lh[dst[i] / RANGE_SZ], 1);
    __syncthreads();
    if (threadIdx.x < NRANGE) bhist1[blockIdx.x * NRANGE + threadIdx.x] = lh[threadIdx.x];
}

// 512 threads = 8 waves; wave r scans range r's 512 per-block counts.
// Also emits range_start[9].
__global__ void scan1_kernel(const int* __restrict__ bhist1, int* __restrict__ cbase1,
                             int* __restrict__ rs) {
    int r = threadIdx.x >> 6, lane = threadIdx.x & 63;
    __shared__ int rtot[NRANGE], roff[NRANGE];
    int excl[8];
    int run = 0;
    #pragma unroll
    for (int seg = 0; seg < 8; ++seg) {
        int b = seg * 64 + lane;
        int v = bhist1[b * NRANGE + r];
        int sc = v;
        #pragma unroll
        for (int off = 1; off < 64; off <<= 1) {
            int y = __shfl_up(sc, off);
            if (lane >= off) sc += y;
        }
        excl[seg] = run + sc - v;
        run += __shfl(sc, 63);
    }
    if (lane == 63) rtot[r] = run;
    __syncthreads();
    if (threadIdx.x == 0) {
        int a = 0;
        for (int i = 0; i < NRANGE; ++i) { roff[i] = a; a += rtot[i]; }
    }
    __syncthreads();
    int base = roff[r];
    #pragma unroll
    for (int seg = 0; seg < 8; ++seg)
        cbase1[(seg * 64 + lane) * NRANGE + r] = base + excl[seg];
    if (threadIdx.x < NRANGE) rs[threadIdx.x] = roff[threadIdx.x];
    if (threadIdx.x == 0) rs[NRANGE] = N_EDGES;
}

// level-1 place: epack1 = (dstLocal14 << 17) | src, range-contiguous
__global__ void place1_kernel(const int* __restrict__ src, const int* __restrict__ dst,
                              const int* __restrict__ cbase1, u32* __restrict__ epack1) {
    __shared__ int cur[NRANGE];
    if (threadIdx.x < NRANGE) cur[threadIdx.x] = cbase1[blockIdx.x * NRANGE + threadIdx.x];
    __syncthreads();
    int s0 = blockIdx.x * CH_PART, s1 = s0 + CH_PART;
    if (s1 > N_EDGES) s1 = N_EDGES;
    for (int i = s0 + threadIdx.x; i < s1; i += 256) {
        int d = dst[i], s = src[i];
        int r = d / RANGE_SZ;
        int dl = d - r * RANGE_SZ;
        int p = atomicAdd(&cur[r], 1);
        epack1[p] = ((u32)dl << 17) | (u32)s;
    }
}

// level-2 histogram: 64 blocks per range, 196 buckets
__global__ void hist2_kernel(const u32* __restrict__ epack1, const int* __restrict__ rs,
                             int* __restrict__ bhist2) {
    __shared__ int lh[SB_PER_RANGE];
    for (int i = threadIdx.x; i < SB_PER_RANGE; i += 256) lh[i] = 0;
    __syncthreads();
    int r = blockIdx.x >> 6, j = blockIdx.x & 63;
    int e0 = rs[r], e1 = rs[r + 1];
    int cs = (e1 - e0 + 63) >> 6;
    int s0 = e0 + j * cs, s1 = s0 + cs;
    if (s1 > e1) s1 = e1;
    for (int i = s0 + threadIdx.x; i < s1; i += 256)
        atomicAdd(&lh[epack1[i] >> 23], 1);
    __syncthreads();
    for (int i = threadIdx.x; i < SB_PER_RANGE; i += 256)
        bhist2[blockIdx.x * SB_PER_RANGE + i] = lh[i];
}

// level-2 scan: 8 blocks (one per range)
__global__ void scan2_kernel(const int* __restrict__ bhist2, const int* __restrict__ rs,
                             int* __restrict__ cbase2, int* __restrict__ bucket_start) {
    int r = blockIdx.x;
    __shared__ int tot[SB_PER_RANGE];
    __shared__ int base[SB_PER_RANGE];
    int sb = threadIdx.x;
    if (sb < SB_PER_RANGE) {
        int s = 0;
        for (int j = 0; j < 64; ++j) s += bhist2[(r * 64 + j) * SB_PER_RANGE + sb];
        tot[sb] = s;
    }
    __syncthreads();
    if (threadIdx.x == 0) {
        int a = 0;
        for (int i = 0; i < SB_PER_RANGE; ++i) { base[i] = a; a += tot[i]; }
    }
    __syncthreads();
    if (sb < SB_PER_RANGE) {
        int run = rs[r] + base[sb];
        bucket_start[r * SB_PER_RANGE + sb] = run;
        for (int j = 0; j < 64; ++j) {
            cbase2[(r * 64 + j) * SB_PER_RANGE + sb] = run;
            run += bhist2[(r * 64 + j) * SB_PER_RANGE + sb];
        }
    }
    if (r == NRANGE - 1 && threadIdx.x == 0) bucket_start[NBUCKET] = N_EDGES;
}

// level-2 place: epack2 = (local6 << 17) | src, bucket-contiguous
__global__ void place2_kernel(const u32* __restrict__ epack1, const int* __restrict__ rs,
                              const int* __restrict__ cbase2, u32* __restrict__ epack2) {
    __shared__ int cur[SB_PER_RANGE];
    for (int i = threadIdx.x; i < SB_PER_RANGE; i += 256)
        cur[i] = cbase2[blockIdx.x * SB_PER_RANGE + i];
    __syncthreads();
    int r = blockIdx.x >> 6, j = blockIdx.x & 63;
    int e0 = rs[r], e1 = rs[r + 1];
    int cs = (e1 - e0 + 63) >> 6;
    int s0 = e0 + j * cs, s1 = s0 + cs;
    if (s1 > e1) s1 = e1;
    for (int i = s0 + threadIdx.x; i < s1; i += 256) {
        u32 e = epack1[i];
        int sb = e >> 23;
        int p = atomicAdd(&cur[sb], 1);
        epack2[p] = e & 0x7FFFFFu;   // keep (dstLocal14 & 63)<<17 | src
    }
}

// per-bucket LDS counting sort -> col + row_ptr  (1568 blocks)
__global__ void sort3_kernel(const u32* __restrict__ epack2, const int* __restrict__ bucket_start,
                             int* __restrict__ row_ptr, int* __restrict__ col) {
    int b = blockIdx.x;
    int r = b / SB_PER_RANGE, sb = b - r * SB_PER_RANGE;
    int node_base = r * RANGE_SZ + sb * 64;
    int nb = r * RANGE_SZ + RANGE_SZ - node_base;
    if (nb > 64) nb = 64;
    int e0 = bucket_start[b], e1 = bucket_start[b + 1];
    __shared__ int hist[64], cur[64];
    if (threadIdx.x < 64) hist[threadIdx.x] = 0;
    __syncthreads();
    for (int i = e0 + threadIdx.x; i < e1; i += 256)
        atomicAdd(&hist[(epack2[i] >> 17) & 63], 1);
    __syncthreads();
    if (threadIdx.x < 64) {   // wave 0
        int v = hist[threadIdx.x];
        int sc = v;
        #pragma unroll
        for (int off = 1; off < 64; off <<= 1) {
            int y = __shfl_up(sc, off);
            if (threadIdx.x >= off) sc += y;
        }
        int ex = e0 + sc - v;
        cur[threadIdx.x] = ex;
        if (threadIdx.x < nb) row_ptr[node_base + threadIdx.x] = ex;
    }
    __syncthreads();
    for (int i = e0 + threadIdx.x; i < e1; i += 256) {
        u32 e = epack2[i];
        int l = (e >> 17) & 63;
        int p = atomicAdd(&cur[l], 1);
        col[p] = (int)(e & 0x1FFFFu);
    }
    if (b == NBUCKET - 1 && threadIdx.x == 0) row_ptr[N_NODES] = N_EDGES;
}

// ---------------- GIN layer ----------------

// quarter-wave (16 lanes x 16B) per node, bf16 gather, 8 edges in flight
__global__ void aggregate_kernel(const ushort* __restrict__ xb, const int* __restrict__ row_ptr,
                                 const int* __restrict__ col, const float* __restrict__ eps_p,
                                 ushort* __restrict__ hb) {
    int gt = blockIdx.x * blockDim.x + threadIdx.x;
    int node = gt >> 4;
    if (node >= N_NODES) return;
    int l16 = threadIdx.x & 15;
    int beg = row_ptr[node], end = row_ptr[node + 1];
    float a0[8] = {0,0,0,0,0,0,0,0};
    float a1[8] = {0,0,0,0,0,0,0,0};
    int e = beg;
    for (; e + 7 < end; e += 8) {
        int s[8];
        #pragma unroll
        for (int j = 0; j < 8; ++j) s[j] = col[e + j];
        u16x8 v[8];
        #pragma unroll
        for (int j = 0; j < 8; ++j)
            v[j] = *(const u16x8*)(xb + ((size_t)s[j] << 7) + l16 * 8);
        #pragma unroll
        for (int j = 0; j < 8; ++j) {
            float* a = (j & 1) ? a1 : a0;
            #pragma unroll
            for (int k = 0; k < 8; ++k) a[k] += b2f(v[j][k]);
        }
    }
    for (; e < end; ++e) {
        int s = col[e];
        u16x8 v = *(const u16x8*)(xb + ((size_t)s << 7) + l16 * 8);
        #pragma unroll
        for (int k = 0; k < 8; ++k) a0[k] += b2f(v[k]);
    }
    float scale = 1.0f + *eps_p;
    u16x8 xi = *(const u16x8*)(xb + ((size_t)node << 7) + l16 * 8);
    u16x8 ho;
    #pragma unroll
    for (int k = 0; k < 8; ++k) {
        float o = a0[k] + a1[k] + scale * b2f(xi[k]);
        ho[k] = f2b(o);
    }
    *(u16x8*)(hb + ((size_t)node << 7) + l16 * 8) = ho;
}

// W[k][n] f32 -> Wt_hi/Wt_lo[n][k] bf16 (transposed, split)
__global__ void wsplit_kernel(const float* __restrict__ W, ushort* __restrict__ wt_hi,
                              ushort* __restrict__ wt_lo) {
    int t = blockIdx.x * blockDim.x + threadIdx.x;
    if (t >= D * D) return;
    int k = t >> 7, n = t & 127;
    float w = W[t];
    ushort hi = f2b(w);
    ushort lo = f2b(w - b2f(hi));
    wt_hi[n * D + k] = hi;
    wt_lo[n * D + k] = lo;
}

// out = relu(h @ W + b); A = bf16 h, W = hi/lo split (2 MFMA per frag pair).
template <bool BF16OUT>
__launch_bounds__(256, 2)
__global__ void gemm_relu_mfma(const ushort* __restrict__ hb,
                               const ushort* __restrict__ wt_hi, const ushort* __restrict__ wt_lo,
                               const float* __restrict__ bias,
                               float* __restrict__ outf, ushort* __restrict__ outb) {
    int wv = threadIdx.x >> 6, lane = threadIdx.x & 63;
    int r0 = blockIdx.x * 128 + wv * 32;
    int arow = lane & 15, agrp = lane >> 4;
    bf16x8 Ah[2][4];
    #pragma unroll
    for (int mf = 0; mf < 2; ++mf) {
        size_t rbase = (size_t)(r0 + mf * 16 + arow) * D;
        #pragma unroll
        for (int kf = 0; kf < 4; ++kf)
            Ah[mf][kf] = *(const bf16x8*)(hb + rbase + kf * 32 + agrp * 8);
    }
    f32x4 acc[2][8];
    #pragma unroll
    for (int mf = 0; mf < 2; ++mf)
        #pragma unroll
        for (int nf = 0; nf < 8; ++nf)
            acc[mf][nf] = (f32x4){0.f, 0.f, 0.f, 0.f};
    #pragma unroll
    for (int nf = 0; nf < 8; ++nf) {
        #pragma unroll
        for (int kf = 0; kf < 4; ++kf) {
            size_t wb = (size_t)(nf * 16 + arow) * D + kf * 32 + agrp * 8;
            bf16x8 bh = *(const bf16x8*)(wt_hi + wb);
            bf16x8 bl = *(const bf16x8*)(wt_lo + wb);
            #pragma unroll
            for (int mf = 0; mf < 2; ++mf) {
                acc[mf][nf] = __builtin_amdgcn_mfma_f32_16x16x32_bf16(Ah[mf][kf], bh, acc[mf][nf], 0, 0, 0);
                acc[mf][nf] = __builtin_amdgcn_mfma_f32_16x16x32_bf16(Ah[mf][kf], bl, acc[mf][nf], 0, 0, 0);
            }
        }
    }
    int crow = agrp * 4;
    #pragma unroll
    for (int mf = 0; mf < 2; ++mf) {
        #pragma unroll
        for (int nf = 0; nf < 8; ++nf) {
            int coln = nf * 16 + arow;
            float b = bias[coln];
            #pragma unroll
            for (int r = 0; r < 4; ++r) {
                int row = r0 + mf * 16 + crow + r;
                if (row < N_NODES) {
                    float val = fmaxf(acc[mf][nf][r] + b, 0.f);
                    if (BF16OUT) outb[(size_t)row * D + coln] = f2b(val);
                    else         outf[(size_t)row * D + coln] = val;
                }
            }
        }
    }
}

// in-place row log_softmax, one wave per node
__global__ void log_softmax_kernel(float* __restrict__ y) {
    int w = (blockIdx.x * blockDim.x + threadIdx.x) >> 6;
    if (w >= N_NODES) return;
    int lane = threadIdx.x & 63;
    float2* y2 = (float2*)y;
    float2 v = y2[(size_t)w * 64 + lane];
    float m = fmaxf(v.x, v.y);
    #pragma unroll
    for (int off = 32; off; off >>= 1) m = fmaxf(m, __shfl_xor(m, off));
    float s = expf(v.x - m) + expf(v.y - m);
    #pragma unroll
    for (int off = 32; off; off >>= 1) s += __shfl_xor(s, off);
    float lse = m + logf(s);
    v.x -= lse;
    v.y -= lse;
    y2[(size_t)w * 64 + lane] = v;
}

extern "C" void kernel_launch(void* const* d_in, const int* in_sizes, int n_in,
                              void* d_out, int out_size, void* d_ws, size_t ws_size,
                              hipStream_t stream) {
    (void)in_sizes; (void)n_in; (void)out_size; (void)ws_size;
    const float* x  = (const float*)d_in[0];
    const int*   ei = (const int*)d_in[1];
    const int*   src = ei;
    const int*   dst = ei + N_EDGES;
    const float* W1 = (const float*)d_in[2];
    const float* b1 = (const float*)d_in[3];
    const float* e1 = (const float*)d_in[4];
    const float* W2 = (const float*)d_in[5];
    const float* b2 = (const float*)d_in[6];
    const float* e2 = (const float*)d_in[7];
    const float* W3 = (const float*)d_in[8];
    const float* b3 = (const float*)d_in[9];
    const float* e3 = (const float*)d_in[10];
    float* out = (float*)d_out;

    char* ws = (char*)d_ws;
    int*    rs           = (int*)ws;                             // 36 B
    int*    bucket_start = (int*)(ws + 1024);                    // 6.3 KB
    int*    bhist1       = (int*)(ws + 8192);                    // 16 KB
    int*    cbase1       = (int*)(ws + 24576);                   // 16 KB
    int*    bhist2       = (int*)(ws + 40960);                   // 401 KB
    int*    cbase2       = (int*)(ws + 458752);                  // 401 KB
    int*    row_ptr      = (int*)(ws + 880640);                  // 400 KB
    int*    col          = (int*)(ws + 1572864);                 // 6.4 MB
    ushort* wt_hi        = (ushort*)(ws + 8388608);              // 32 KB
    ushort* wt_lo        = (ushort*)(ws + 8454144);              // 32 KB
    ushort* xb           = (ushort*)(ws + 9437184);              // 25.6 MB
    ushort* hb           = (ushort*)(ws + 35651584);             // 25.6 MB
    u32*    epack1       = (u32*)(ws + 35651584);                // 6.4 MB (aliases hb; dead before agg)
    u32*    epack2       = (u32*)(ws + 42991616);                // 6.4 MB (aliases hb; dead before agg)

    x2b_kernel<<<(N_NODES * D / 4 + 255) / 256, 256, 0, stream>>>(x, xb);

    hist1_kernel<<<G_PART, 256, 0, stream>>>(dst, bhist1);
    scan1_kernel<<<1, 512, 0, stream>>>(bhist1, cbase1, rs);
    place1_kernel<<<G_PART, 256, 0, stream>>>(src, dst, cbase1, epack1);
    hist2_kernel<<<G_PART, 256, 0, stream>>>(epack1, rs, bhist2);
    scan2_kernel<<<NRANGE, 256, 0, stream>>>(bhist2, rs, cbase2, bucket_start);
    place2_kernel<<<G_PART, 256, 0, stream>>>(epack1, rs, cbase2, epack2);
    sort3_kernel<<<NBUCKET, 256, 0, stream>>>(epack2, bucket_start, row_ptr, col);

    const int aggGrid = (N_NODES * 16 + 255) / 256;   // 6250
    const int gemmGrid = (N_NODES + 127) / 128;       // 782

    // layer 1
    aggregate_kernel<<<aggGrid, 256, 0, stream>>>(xb, row_ptr, col, e1, hb);
    wsplit_kernel<<<64, 256, 0, stream>>>(W1, wt_hi, wt_lo);
    gemm_relu_mfma<true><<<gemmGrid, 256, 0, stream>>>(hb, wt_hi, wt_lo, b1, nullptr, xb);
    // layer 2
    aggregate_kernel<<<aggGrid, 256, 0, stream>>>(xb, row_ptr, col, e2, hb);
    wsplit_kernel<<<64, 256, 0, stream>>>(W2, wt_hi, wt_lo);
    gemm_relu_mfma<true><<<gemmGrid, 256, 0, stream>>>(hb, wt_hi, wt_lo, b2, nullptr, xb);
    // layer 3
    aggregate_kernel<<<aggGrid, 256, 0, stream>>>(xb, row_ptr, col, e3, hb);
    wsplit_kernel<<<64, 256, 0, stream>>>(W3, wt_hi, wt_lo);
    gemm_relu_mfma<false><<<gemmGrid, 256, 0, stream>>>(hb, wt_hi, wt_lo, b3, out, nullptr);

    log_softmax_kernel<<<(N_NODES * 64 + 255) / 256, 256, 0, stream>>>(out);
}